// Round 10
// baseline (128.360 us; speedup 1.0000x reference)
//
#include <hip/hip_runtime.h>

#define NC 32
#define DC 16
#define LSEQ 2048

// ---------------------------------------------------------------------------
// K1: zero v1/v2 (atomic targets) + per-block partial column sums of u.
// grid 256 (b = bid>>3, chunk = bid&7), 256 threads. Writes v0p[bid][64].
// ---------------------------------------------------------------------------
__global__ __launch_bounds__(256) void k_sum_u(const float* __restrict__ u,
                                               float* __restrict__ v0p,
                                               float* __restrict__ v1,
                                               float* __restrict__ v2) {
    int gid = blockIdx.x * 256 + threadIdx.x;   // 0..65535
    v1[gid] = 0.f;                              // 32*2048 floats
    v2[gid] = 0.f;
    int b  = blockIdx.x >> 3;
    int l0 = (blockIdx.x & 7) * 256;
    int q  = threadIdx.x & 15;   // float4 column
    int r  = threadIdx.x >> 4;   // row offset 0..15
    const float4* u4 = (const float4*)u;
    float4 acc = {0.f, 0.f, 0.f, 0.f};
#pragma unroll
    for (int j = 0; j < 16; ++j) {
        int l = l0 + r + 16 * j;
        float4 x = u4[(b * LSEQ + l) * 16 + q];
        acc.x += x.x; acc.y += x.y; acc.z += x.z; acc.w += x.w;
    }
    __shared__ float red[16][64];
    red[r][q * 4 + 0] = acc.x;
    red[r][q * 4 + 1] = acc.y;
    red[r][q * 4 + 2] = acc.z;
    red[r][q * 4 + 3] = acc.w;
    __syncthreads();
    if (threadIdx.x < 64) {
        float s = 0.f;
#pragma unroll
        for (int rr = 0; rr < 16; ++rr) s += red[rr][threadIdx.x];
        v0p[blockIdx.x * 64 + threadIdx.x] = s;   // partial, no atomics
    }
}

// ---------------------------------------------------------------------------
// k_route v10: r6 body + cheap fused caps HEAD + atomicAdd output.
// grid 512 (b = bid>>4, ch = bid&15 -> 128 l's), 256 threads = 4 waves
// (2 blocks/CU at 64000 B LDS).
// Head (redundant per block; inputs tiny/L2-hot — lesson of r8):
//   ITER0: fold v0p (8x64 = 2 KB) -> v0, x1/32 (uniform c).
//   else : read v_in[b][2048] (8 KB, already folded by atomics).
//   H2: s[n][d] = v@W_col, L2-normalize -> oS.  H3: wtil -> wS (LDS only).
// Body (r6 verbatim): phase A 4l x 4n logits (n = lc+8*jj, conflict-free),
// in-register softmax, phase B 4n x 8d, cross-wave fold.
// Tail: atomicAdd block partial into v_out[b][2048] (fire-and-forget).
// ---------------------------------------------------------------------------
template <int ITER0>
__global__ __launch_bounds__(256) void k_route(const float* __restrict__ u,
                                               const float* __restrict__ W,
                                               const float* __restrict__ vin,
                                               float* __restrict__ vout) {
    int b    = blockIdx.x >> 4;
    int ch   = blockIdx.x & 15;
    int l0   = ch * 128;
    int t    = threadIdx.x;
    int w    = t >> 6;
    int lane = t & 63;
    int lr   = lane & 7;   // l = w*32 + lr + 8*i
    int lc   = lane >> 3;  // n = lc + 8*jj
    int dr   = lane & 7;   // phase B: d = dr*8 .. dr*8+7
    int ng   = lane >> 3;  // phase B: n = ng + 8*jj

    __shared__ float uS[128 * 68];        // 34816 B; red[2][2048] overlay later
    __shared__ float wS[32 * 68];         //  8704 B
    __shared__ float cS[128 * 36];        // 18432 B; head vS overlay first
    __shared__ float oS[512];             //  2048 B  (total 64000 B)
    float4* uS4 = (float4*)uS;
    float4* wS4 = (float4*)wS;
    float4* c4  = (float4*)cS;

    // ---- stage u-tile [128][64] (coalesced; in flight during head) ----
    const float4* ug = (const float4*)(u + (b * LSEQ + l0) * 64);
#pragma unroll
    for (int r = 0; r < 8; ++r) {
        int idx = t + 256 * r;                 // 0..2047 = row*16 + col4
        uS4[(idx >> 4) * 17 + (idx & 15)] = ug[idx];
    }

    // ---- HEAD H1: v -> vS (in cS) ----
    float* vS = cS;                            // ITER0: [64]; else [32][68]
    if (ITER0) {
        if (t < 64) {
            float s = 0.f;
#pragma unroll
            for (int c = 0; c < 8; ++c) s += vin[(b * 8 + c) * 64 + t];
            vS[t] = s * (1.f / 32.f);
        }
    } else {
        const float4* vp = (const float4*)(vin + b * 2048);
#pragma unroll
        for (int r = 0; r < 2; ++r) {
            int idx = t + 256 * r;             // 0..511: n = idx>>4, c4 = idx&15
            ((float4*)vS)[(idx >> 4) * 17 + (idx & 15)] = vp[idx];
        }
    }
    __syncthreads();

    // ---- HEAD H2: s[n][d] = v[n]@W[:,n*16+d]; L2-normalize -> oS ----
#pragma unroll
    for (int rep = 0; rep < 2; ++rep) {
        int nd = t + 256 * rep;                // n = nd>>4, d = nd&15
        const float* vrow = ITER0 ? vS : vS + (nd >> 4) * 68;
        float s = 0.f;
#pragma unroll 8
        for (int i = 0; i < 64; ++i)
            s = fmaf(vrow[i], W[i * (NC * DC) + nd], s);
        float s2 = s * s;
        s2 += __shfl_xor(s2, 1);
        s2 += __shfl_xor(s2, 2);
        s2 += __shfl_xor(s2, 4);
        s2 += __shfl_xor(s2, 8);
        oS[nd] = s / sqrtf(s2 + 1e-7f);
    }
    __syncthreads();

    // ---- HEAD H3: wS[n][i] = sum_d W[i][n*16+d] * o[n][d] (stride-68) ----
#pragma unroll
    for (int rep = 0; rep < 2; ++rep) {
        int f4 = t + 256 * rep;                // 0..511: n = f4>>4, i4 = f4&15
        int n = f4 >> 4, i4 = f4 & 15;
        const float4* o4 = (const float4*)(oS + n * DC);
        float4 ov0 = o4[0], ov1 = o4[1], ov2 = o4[2], ov3 = o4[3];
        float4 wv;
        float* wvp = (float*)&wv;
#pragma unroll
        for (int k = 0; k < 4; ++k) {
            int i = i4 * 4 + k;
            const float4* wr = (const float4*)(W + i * (NC * DC) + n * DC);
            float4 w0 = wr[0], w1 = wr[1], w2 = wr[2], w3 = wr[3];
            float acc = w0.x * ov0.x + w0.y * ov0.y + w0.z * ov0.z + w0.w * ov0.w;
            acc += w1.x * ov1.x + w1.y * ov1.y + w1.z * ov1.z + w1.w * ov1.w;
            acc += w2.x * ov2.x + w2.y * ov2.y + w2.z * ov2.z + w2.w * ov2.w;
            acc += w3.x * ov3.x + w3.y * ov3.y + w3.z * ov3.z + w3.w * ov3.w;
            wvp[k] = acc;
        }
        wS4[n * 17 + i4] = wv;
    }
    __syncthreads();                           // wS + uS ready

    // ---- phase A: logits (per-lane 4l x 4n register tile) ----
    float acc[4][4];
#pragma unroll
    for (int i = 0; i < 4; ++i)
#pragma unroll
        for (int jj = 0; jj < 4; ++jj) acc[i][jj] = 0.f;
    int arow = w * 32 + lr;
#pragma unroll 4
    for (int k4 = 0; k4 < 16; ++k4) {
        float4 wf[4];
#pragma unroll
        for (int jj = 0; jj < 4; ++jj) wf[jj] = wS4[(lc + 8 * jj) * 17 + k4];
#pragma unroll
        for (int i = 0; i < 4; ++i) {
            float4 a = uS4[(arow + 8 * i) * 17 + k4];
#pragma unroll
            for (int jj = 0; jj < 4; ++jj) {
                acc[i][jj] = fmaf(a.x, wf[jj].x, acc[i][jj]);
                acc[i][jj] = fmaf(a.y, wf[jj].y, acc[i][jj]);
                acc[i][jj] = fmaf(a.z, wf[jj].z, acc[i][jj]);
                acc[i][jj] = fmaf(a.w, wf[jj].w, acc[i][jj]);
            }
        }
    }

    // ---- softmax over n (4 regs x 8 lc-groups) per l-row i ----
#pragma unroll
    for (int i = 0; i < 4; ++i) {
        float m = fmaxf(fmaxf(acc[i][0], acc[i][1]), fmaxf(acc[i][2], acc[i][3]));
        m = fmaxf(m, __shfl_xor(m, 8));
        m = fmaxf(m, __shfl_xor(m, 16));
        m = fmaxf(m, __shfl_xor(m, 32));
        float e0 = __expf(acc[i][0] - m), e1 = __expf(acc[i][1] - m);
        float e2 = __expf(acc[i][2] - m), e3 = __expf(acc[i][3] - m);
        float ss = e0 + e1 + e2 + e3;
        ss += __shfl_xor(ss, 8);
        ss += __shfl_xor(ss, 16);
        ss += __shfl_xor(ss, 32);
        float inv = 1.f / ss;
        float4 cvv = {e0 * inv, e1 * inv, e2 * inv, e3 * inv};
        c4[(arow + 8 * i) * 9 + lc] = cvv;     // xyzw = n = lc, lc+8, lc+16, lc+24
    }
    __syncthreads();

    // ---- phase B: V[n = ng+8jj][i = dr*8..+7] += sum_l c[l][n]*u[l][i] ----
    float vacc[4][8];
#pragma unroll
    for (int jj = 0; jj < 4; ++jj)
#pragma unroll
        for (int k = 0; k < 8; ++k) vacc[jj][k] = 0.f;
#pragma unroll 8
    for (int lrel = 0; lrel < 32; ++lrel) {
        int row = w * 32 + lrel;
        float4 cv = c4[row * 9 + ng];
        const float4* ur = uS4 + row * 17 + dr * 2;
        float4 u0 = ur[0], u1 = ur[1];
        float* cp = (float*)&cv;
#pragma unroll
        for (int jj = 0; jj < 4; ++jj) {
            float c = cp[jj];
            vacc[jj][0] = fmaf(c, u0.x, vacc[jj][0]);
            vacc[jj][1] = fmaf(c, u0.y, vacc[jj][1]);
            vacc[jj][2] = fmaf(c, u0.z, vacc[jj][2]);
            vacc[jj][3] = fmaf(c, u0.w, vacc[jj][3]);
            vacc[jj][4] = fmaf(c, u1.x, vacc[jj][4]);
            vacc[jj][5] = fmaf(c, u1.y, vacc[jj][5]);
            vacc[jj][6] = fmaf(c, u1.z, vacc[jj][6]);
            vacc[jj][7] = fmaf(c, u1.w, vacc[jj][7]);
        }
    }
    __syncthreads();                   // all uS reads done -> overlay red on uS

    // ---- cross-wave fold: waves 1,3 write; 0,2 add; halves fold ----
    float* red   = uS;                 // [2][32][64] floats (16 KB)
    float* rbase = red + (w >> 1) * 2048;
    if (w & 1) {
#pragma unroll
        for (int jj = 0; jj < 4; ++jj) {
            float4* rp = (float4*)(rbase + (ng + 8 * jj) * 64 + dr * 8);
            float4 r0 = {vacc[jj][0], vacc[jj][1], vacc[jj][2], vacc[jj][3]};
            float4 r1 = {vacc[jj][4], vacc[jj][5], vacc[jj][6], vacc[jj][7]};
            rp[0] = r0;
            rp[1] = r1;
        }
    }
    __syncthreads();
    if (!(w & 1)) {
#pragma unroll
        for (int jj = 0; jj < 4; ++jj) {
            float4* rp = (float4*)(rbase + (ng + 8 * jj) * 64 + dr * 8);
            float4 r0 = rp[0], r1 = rp[1];
            r0.x += vacc[jj][0]; r0.y += vacc[jj][1];
            r0.z += vacc[jj][2]; r0.w += vacc[jj][3];
            r1.x += vacc[jj][4]; r1.y += vacc[jj][5];
            r1.z += vacc[jj][6]; r1.w += vacc[jj][7];
            rp[0] = r0;
            rp[1] = r1;
        }
    }
    __syncthreads();
    // ---- fold halves + atomicAdd into vout[b][2048] (fire-and-forget) ----
    float4* red4 = (float4*)red;
#pragma unroll
    for (int s = 0; s < 2; ++s) {
        int idx4 = t + 256 * s;               // 0..511
        float4 a  = red4[idx4];
        float4 c2 = red4[512 + idx4];
        float* vp = vout + b * 2048 + idx4 * 4;
        atomicAdd(vp + 0, a.x + c2.x);
        atomicAdd(vp + 1, a.y + c2.y);
        atomicAdd(vp + 2, a.z + c2.z);
        atomicAdd(vp + 3, a.w + c2.w);
    }
}

// ---------------------------------------------------------------------------
// K4: final caps from the (already-folded) v2[b][n][64].
// grid 256 (b = bid>>3, ng = bid&7 -> capsules ng*4..+3), 64 threads.
// ---------------------------------------------------------------------------
__global__ __launch_bounds__(64) void k_caps_out(const float* __restrict__ v,
                                                 const float* __restrict__ W,
                                                 float* __restrict__ out) {
    int b  = blockIdx.x >> 3;
    int ng = blockIdx.x & 7;
    int t  = threadIdx.x;
    __shared__ float vS[4][72];
    {
        int row = t >> 4, col4 = t & 15;
        float4 x = ((const float4*)(v + b * 2048 + (ng * 4 + row) * 64))[col4];
        ((float4*)&vS[row][0])[col4] = x;
    }
    __syncthreads();
    int n4 = t >> 4, d = t & 15;
    int n  = ng * 4 + n4;
    const float* vrow = &vS[n4][0];
    float s = 0.f;
#pragma unroll
    for (int i = 0; i < 64; ++i)
        s = fmaf(vrow[i], W[i * (NC * DC) + n * DC + d], s);
    float s2 = s * s;
#pragma unroll
    for (int off = 8; off >= 1; off >>= 1) s2 += __shfl_xor(s2, off, 16);
    out[b * (NC * DC) + n * DC + d] = s / sqrtf(s2 + 1e-7f);
}

extern "C" void kernel_launch(void* const* d_in, const int* in_sizes, int n_in,
                              void* d_out, int out_size, void* d_ws, size_t ws_size,
                              hipStream_t stream) {
    const float* u = (const float*)d_in[0];  // [32, 2048, 64] f32
    const float* W = (const float*)d_in[1];  // [1, 64, 512]  f32
    float* out = (float*)d_out;              // [32, 32, 16]  f32
    float* ws  = (float*)d_ws;
    float* v0p = ws;                   // 256*64  = 16384 floats
    float* v1  = ws + 16384;           // 32*2048 = 65536 floats
    float* v2  = ws + 16384 + 65536;   // 32*2048 = 65536 floats

    k_sum_u<<<256, 256, 0, stream>>>(u, v0p, v1, v2);        // + zero v1/v2
    k_route<1><<<512, 256, 0, stream>>>(u, W, v0p, v1);      // head: caps0
    k_route<0><<<512, 256, 0, stream>>>(u, W, v1, v2);       // head: caps1
    k_caps_out<<<256, 64, 0, stream>>>(v2, W, out);
}

// Round 11
// 111.344 us; speedup vs baseline: 1.1528x; 1.1528x over previous
//
#include <hip/hip_runtime.h>

#define NC 32
#define DC 16
#define LSEQ 2048

// ---------------------------------------------------------------------------
// k_sum_u: per-block partial column sums of u over 256 l's. (r6 verbatim)
// grid 256 (b = bid>>3, chunk = bid&7), 256 threads. Writes v0p[bid][64].
// ---------------------------------------------------------------------------
__global__ __launch_bounds__(256) void k_sum_u(const float* __restrict__ u,
                                               float* __restrict__ v0p) {
    int b  = blockIdx.x >> 3;
    int l0 = (blockIdx.x & 7) * 256;
    int q  = threadIdx.x & 15;   // float4 column
    int r  = threadIdx.x >> 4;   // row offset 0..15
    const float4* u4 = (const float4*)u;
    float4 acc = {0.f, 0.f, 0.f, 0.f};
#pragma unroll
    for (int j = 0; j < 16; ++j) {
        int l = l0 + r + 16 * j;
        float4 x = u4[(b * LSEQ + l) * 16 + q];
        acc.x += x.x; acc.y += x.y; acc.z += x.z; acc.w += x.w;
    }
    __shared__ float red[16][64];
    red[r][q * 4 + 0] = acc.x;
    red[r][q * 4 + 1] = acc.y;
    red[r][q * 4 + 2] = acc.z;
    red[r][q * 4 + 3] = acc.w;
    __syncthreads();
    if (threadIdx.x < 64) {
        float s = 0.f;
#pragma unroll
        for (int rr = 0; rr < 16; ++rr) s += red[rr][threadIdx.x];
        v0p[blockIdx.x * 64 + threadIdx.x] = s;   // partial, no atomics
    }
}

// ---------------------------------------------------------------------------
// k_caps v11: grid 32 (one block per b), 512 threads = 8 waves (vs r6's
// 64-thread 1-wave blocks -> latency-exposed). Fold + s = v@W + normalize
// (+ wtil unless FINAL). FP order identical to r6's k_caps.
//   BCAST: vin = v0p, 8 partials x 64, uniform c -> single 64-vec (x vscale).
//   else : vin = vpart, 16 chunk partials x 2048 (route grid 512 = b*16+ch).
// ---------------------------------------------------------------------------
template <bool BCAST, bool FINAL>
__global__ __launch_bounds__(512) void k_caps(const float* __restrict__ vin,
                                              const float* __restrict__ W,
                                              float* __restrict__ wtil,
                                              float* __restrict__ out,
                                              float vscale) {
    int b = blockIdx.x;
    int t = threadIdx.x;
    __shared__ float vS[32 * 68];      // padded rows (or [64] for BCAST)
    __shared__ float oS[512];

    // ---- fold partials -> vS ----
    if (BCAST) {
        if (t < 64) {
            float s = 0.f;
#pragma unroll
            for (int ch = 0; ch < 8; ++ch) s += vin[(b * 8 + ch) * 64 + t];
            vS[t] = s * vscale;
        }
    } else {
        const float4* vp = (const float4*)(vin + b * 16 * 2048);
        float4 a = {0.f, 0.f, 0.f, 0.f};
#pragma unroll
        for (int ch = 0; ch < 16; ++ch) {
            float4 x = vp[ch * 512 + t];       // coalesced across 512 threads
            a.x += x.x; a.y += x.y; a.z += x.z; a.w += x.w;
        }
        ((float4*)vS)[(t >> 4) * 17 + (t & 15)] = a;
    }
    __syncthreads();

    // ---- s[n][d] = v[n] @ W[:, n*16+d]; L2-normalize over d -> o ----
    int n = t >> 4, d = t & 15;
    const float* vrow = BCAST ? vS : vS + n * 68;
    float s = 0.f;
#pragma unroll 8
    for (int i = 0; i < 64; ++i)
        s = fmaf(vrow[i], W[i * (NC * DC) + t], s);   // W col t = n*16+d, coalesced
    float s2 = s * s;
    s2 += __shfl_xor(s2, 1);
    s2 += __shfl_xor(s2, 2);
    s2 += __shfl_xor(s2, 4);
    s2 += __shfl_xor(s2, 8);
    float o = s / sqrtf(s2 + 1e-7f);
    (void)d;

    if (FINAL) {
        out[b * (NC * DC) + t] = o;       // out[b][n][d], coalesced
        return;
    }
    oS[t] = o;
    __syncthreads();

    // ---- wtil[b][n][i] = sum_d W[i][n*16+d] * o[n][d]; thread -> (n, i4) ----
    {
        int i4 = t & 15;
        const float4* o4 = (const float4*)(oS + n * DC);
        float4 ov0 = o4[0], ov1 = o4[1], ov2 = o4[2], ov3 = o4[3];
        float4 wv;
        float* wvp = (float*)&wv;
#pragma unroll
        for (int k = 0; k < 4; ++k) {
            int i = i4 * 4 + k;
            const float4* wr = (const float4*)(W + i * (NC * DC) + n * DC);
            float4 w0 = wr[0], w1 = wr[1], w2 = wr[2], w3 = wr[3];
            float acc = w0.x * ov0.x + w0.y * ov0.y + w0.z * ov0.z + w0.w * ov0.w;
            acc += w1.x * ov1.x + w1.y * ov1.y + w1.z * ov1.z + w1.w * ov1.w;
            acc += w2.x * ov2.x + w2.y * ov2.y + w2.z * ov2.z + w2.w * ov2.w;
            acc += w3.x * ov3.x + w3.y * ov3.y + w3.z * ov3.z + w3.w * ov3.w;
            wvp[k] = acc;
        }
        ((float4*)wtil)[(b * (NC * 64) + n * 64 + i4 * 4) >> 2] = wv;
    }
}

// ---------------------------------------------------------------------------
// k_route v6 (r6 verbatim — measured best): grid 512 (b = bid>>4, ch =
// bid&15 -> 128 l's), 256 threads = 4 waves (2/SIMD at 2 blocks/CU).
// ---------------------------------------------------------------------------
__global__ __launch_bounds__(256) void k_route(const float* __restrict__ u,
                                               const float* __restrict__ wtil,
                                               float* __restrict__ vpart) {
    int b    = blockIdx.x >> 4;
    int ch   = blockIdx.x & 15;
    int l0   = ch * 128;
    int t    = threadIdx.x;
    int w    = t >> 6;
    int lane = t & 63;
    int lr   = lane & 7;   // l = w*32 + lr + 8*i
    int lc   = lane >> 3;  // n = lc + 8*jj
    int dr   = lane & 7;   // phase B: d = dr*8 .. dr*8+7
    int ng   = lane >> 3;  // phase B: n = ng + 8*jj

    __shared__ float uS[128 * 68];        // 34816 B; red[2][2048] overlay later
    __shared__ float wS[32 * 68];         //  8704 B
    __shared__ float cS[128 * 36];        // 18432 B: c rows, stride 9 float4
    float4* uS4 = (float4*)uS;
    float4* wS4 = (float4*)wS;
    float4* c4  = (float4*)cS;

    // ---- stage u-tile [128][64] and w-tile [32][64] (coalesced) ----
    const float4* ug = (const float4*)(u + (b * LSEQ + l0) * 64);
#pragma unroll
    for (int r = 0; r < 8; ++r) {
        int idx = t + 256 * r;                 // 0..2047 = row*16 + col4
        uS4[(idx >> 4) * 17 + (idx & 15)] = ug[idx];
    }
    const float4* wg = (const float4*)(wtil + b * (NC * 64));
#pragma unroll
    for (int r = 0; r < 2; ++r) {
        int idx = t + 256 * r;                 // 0..511
        wS4[(idx >> 4) * 17 + (idx & 15)] = wg[idx];
    }
    __syncthreads();

    // ---- phase A: logits (per-lane 4l x 4n register tile) ----
    float acc[4][4];
#pragma unroll
    for (int i = 0; i < 4; ++i)
#pragma unroll
        for (int jj = 0; jj < 4; ++jj) acc[i][jj] = 0.f;
    int arow = w * 32 + lr;
#pragma unroll 4
    for (int k4 = 0; k4 < 16; ++k4) {
        float4 wf[4];
#pragma unroll
        for (int jj = 0; jj < 4; ++jj) wf[jj] = wS4[(lc + 8 * jj) * 17 + k4];
#pragma unroll
        for (int i = 0; i < 4; ++i) {
            float4 a = uS4[(arow + 8 * i) * 17 + k4];
#pragma unroll
            for (int jj = 0; jj < 4; ++jj) {
                acc[i][jj] = fmaf(a.x, wf[jj].x, acc[i][jj]);
                acc[i][jj] = fmaf(a.y, wf[jj].y, acc[i][jj]);
                acc[i][jj] = fmaf(a.z, wf[jj].z, acc[i][jj]);
                acc[i][jj] = fmaf(a.w, wf[jj].w, acc[i][jj]);
            }
        }
    }

    // ---- softmax over n (4 regs x 8 lc-groups) per l-row i ----
#pragma unroll
    for (int i = 0; i < 4; ++i) {
        float m = fmaxf(fmaxf(acc[i][0], acc[i][1]), fmaxf(acc[i][2], acc[i][3]));
        m = fmaxf(m, __shfl_xor(m, 8));
        m = fmaxf(m, __shfl_xor(m, 16));
        m = fmaxf(m, __shfl_xor(m, 32));
        float e0 = __expf(acc[i][0] - m), e1 = __expf(acc[i][1] - m);
        float e2 = __expf(acc[i][2] - m), e3 = __expf(acc[i][3] - m);
        float ss = e0 + e1 + e2 + e3;
        ss += __shfl_xor(ss, 8);
        ss += __shfl_xor(ss, 16);
        ss += __shfl_xor(ss, 32);
        float inv = 1.f / ss;
        float4 cvv = {e0 * inv, e1 * inv, e2 * inv, e3 * inv};
        c4[(arow + 8 * i) * 9 + lc] = cvv;     // xyzw = n = lc, lc+8, lc+16, lc+24
    }
    __syncthreads();

    // ---- phase B: V[n = ng+8jj][d = dr*8..+7] += sum_l c[l][n]*u[l][d] ----
    float vacc[4][8];
#pragma unroll
    for (int jj = 0; jj < 4; ++jj)
#pragma unroll
        for (int k = 0; k < 8; ++k) vacc[jj][k] = 0.f;
#pragma unroll 8
    for (int lrel = 0; lrel < 32; ++lrel) {
        int row = w * 32 + lrel;
        float4 cv = c4[row * 9 + ng];
        const float4* ur = uS4 + row * 17 + dr * 2;
        float4 u0 = ur[0], u1 = ur[1];
        float* cp = (float*)&cv;
#pragma unroll
        for (int jj = 0; jj < 4; ++jj) {
            float c = cp[jj];
            vacc[jj][0] = fmaf(c, u0.x, vacc[jj][0]);
            vacc[jj][1] = fmaf(c, u0.y, vacc[jj][1]);
            vacc[jj][2] = fmaf(c, u0.z, vacc[jj][2]);
            vacc[jj][3] = fmaf(c, u0.w, vacc[jj][3]);
            vacc[jj][4] = fmaf(c, u1.x, vacc[jj][4]);
            vacc[jj][5] = fmaf(c, u1.y, vacc[jj][5]);
            vacc[jj][6] = fmaf(c, u1.z, vacc[jj][6]);
            vacc[jj][7] = fmaf(c, u1.w, vacc[jj][7]);
        }
    }
    __syncthreads();                   // all uS reads done -> overlay red on uS

    // ---- cross-wave fold: waves 1,3 write; 0,2 add; halves fold + store ----
    float* red   = uS;                 // [2][32][64] floats (16 KB)
    float* rbase = red + (w >> 1) * 2048;
    if (w & 1) {
#pragma unroll
        for (int jj = 0; jj < 4; ++jj) {
            float4* rp = (float4*)(rbase + (ng + 8 * jj) * 64 + dr * 8);
            float4 r0 = {vacc[jj][0], vacc[jj][1], vacc[jj][2], vacc[jj][3]};
            float4 r1 = {vacc[jj][4], vacc[jj][5], vacc[jj][6], vacc[jj][7]};
            rp[0] = r0;
            rp[1] = r1;
        }
    }
    __syncthreads();
    if (!(w & 1)) {
#pragma unroll
        for (int jj = 0; jj < 4; ++jj) {
            float4* rp = (float4*)(rbase + (ng + 8 * jj) * 64 + dr * 8);
            float4 r0 = rp[0], r1 = rp[1];
            r0.x += vacc[jj][0]; r0.y += vacc[jj][1];
            r0.z += vacc[jj][2]; r0.w += vacc[jj][3];
            r1.x += vacc[jj][4]; r1.y += vacc[jj][5];
            r1.z += vacc[jj][6]; r1.w += vacc[jj][7];
            rp[0] = r0;
            rp[1] = r1;
        }
    }
    __syncthreads();
    // fold the 2 halves and store the block partial (coalesced)
    float4* red4 = (float4*)red;
    float4* vp4  = (float4*)(vpart + blockIdx.x * 2048);
#pragma unroll
    for (int s = 0; s < 2; ++s) {
        int idx4 = t + 256 * s;               // 0..511
        float4 a  = red4[idx4];
        float4 c2 = red4[512 + idx4];
        float4 o  = {a.x + c2.x, a.y + c2.y, a.z + c2.z, a.w + c2.w};
        vp4[idx4] = o;
    }
}

extern "C" void kernel_launch(void* const* d_in, const int* in_sizes, int n_in,
                              void* d_out, int out_size, void* d_ws, size_t ws_size,
                              hipStream_t stream) {
    const float* u = (const float*)d_in[0];  // [32, 2048, 64] f32
    const float* W = (const float*)d_in[1];  // [1, 64, 512]  f32
    float* out = (float*)d_out;              // [32, 32, 16]  f32
    float* ws  = (float*)d_ws;
    float* v0p   = ws;                 // 256*64      = 16384 floats
    float* wt    = ws + 16384;         // 32*32*64    = 65536 floats
    float* vpart = ws + 16384 + 65536; // 512*2048    = 1048576 floats (~4 MB)

    // iter 0: uniform c = 1/32 -> column sum
    k_sum_u<<<256, 256, 0, stream>>>(u, v0p);
    k_caps<true, false><<<32, 512, 0, stream>>>(v0p, W, wt, nullptr, 1.0f / 32.0f);
    // iter 1
    k_route<<<512, 256, 0, stream>>>(u, wt, vpart);
    k_caps<false, false><<<32, 512, 0, stream>>>(vpart, W, wt, nullptr, 1.0f);
    // iter 2
    k_route<<<512, 256, 0, stream>>>(u, wt, vpart);
    k_caps<false, true><<<32, 512, 0, stream>>>(vpart, W, nullptr, out, 1.0f);
}

// Round 13
// 100.498 us; speedup vs baseline: 1.2772x; 1.1079x over previous
//
#include <hip/hip_runtime.h>

#define NC 32
#define DC 16
#define LSEQ 2048

// ---------------------------------------------------------------------------
// k_sum_u: per-block partial column sums of u over 256 l's.
// grid 256 (b = bid>>3, chunk = bid&7), 256 threads. Writes v0p[bid][64].
// ---------------------------------------------------------------------------
__global__ __launch_bounds__(256) void k_sum_u(const float* __restrict__ u,
                                               float* __restrict__ v0p) {
    int b  = blockIdx.x >> 3;
    int l0 = (blockIdx.x & 7) * 256;
    int q  = threadIdx.x & 15;   // float4 column
    int r  = threadIdx.x >> 4;   // row offset 0..15
    const float4* u4 = (const float4*)u;
    float4 acc = {0.f, 0.f, 0.f, 0.f};
#pragma unroll
    for (int j = 0; j < 16; ++j) {
        int l = l0 + r + 16 * j;
        float4 x = u4[(b * LSEQ + l) * 16 + q];
        acc.x += x.x; acc.y += x.y; acc.z += x.z; acc.w += x.w;
    }
    __shared__ float red[16][64];
    red[r][q * 4 + 0] = acc.x;
    red[r][q * 4 + 1] = acc.y;
    red[r][q * 4 + 2] = acc.z;
    red[r][q * 4 + 3] = acc.w;
    __syncthreads();
    if (threadIdx.x < 64) {
        float s = 0.f;
#pragma unroll
        for (int rr = 0; rr < 16; ++rr) s += red[rr][threadIdx.x];
        v0p[blockIdx.x * 64 + threadIdx.x] = s;   // partial, no atomics
    }
}

// ---------------------------------------------------------------------------
// k_caps: fold partials -> v[b][n][64]; s = v@W_n; o = L2-normalize(s);
// wtil[b][n][i] = (W_n @ o_n)[i]  (unless FINAL: write o to out).
// grid 256 (b = bid>>3, ng = bid&7 -> capsules ng*4..ng*4+3), 64 threads.
// NOTE r11 measured: 32x512 caps geometry is SLOWER (1/8th of chip used);
// this 256x64 shape is the measured best. Do not "widen" it again.
// ---------------------------------------------------------------------------
template <bool BCAST, bool FINAL>
__global__ __launch_bounds__(64) void k_caps(const float* __restrict__ v,
                                             const float* __restrict__ W,
                                             float* __restrict__ wtil,
                                             float* __restrict__ out,
                                             float vscale) {
    int b  = blockIdx.x >> 3;
    int ng = blockIdx.x & 7;
    int t  = threadIdx.x;
    __shared__ float vS[4][72];   // 72-float row stride: float4-aligned, pad
    __shared__ float oS[4][16];
    if (BCAST) {
        // fold 8 partial sums of k_sum_u
        float s = 0.f;
#pragma unroll
        for (int ch = 0; ch < 8; ++ch) s += v[(b * 8 + ch) * 64 + t];
        s *= vscale;
#pragma unroll
        for (int n4 = 0; n4 < 4; ++n4) vS[n4][t] = s;   // replicate
    } else {
        // fold 16 route partials: v layout [b][ch][n*64+d], need rows ng*4..+3
        int row = t >> 4, col4 = t & 15;
        const float4* v4 = (const float4*)v;
        float4 a = {0.f, 0.f, 0.f, 0.f};
#pragma unroll
        for (int ch = 0; ch < 16; ++ch) {
            float4 x = v4[(b * 16 + ch) * 512 + (ng * 4 + row) * 16 + col4];
            a.x += x.x; a.y += x.y; a.z += x.z; a.w += x.w;
        }
        ((float4*)&vS[row][0])[col4] = a;
    }
    __syncthreads();
    int n4 = t >> 4, d = t & 15;
    int n  = ng * 4 + n4;
    const float* vrow = &vS[n4][0];
    float s = 0.f;
#pragma unroll
    for (int i = 0; i < 64; ++i)
        s = fmaf(vrow[i], W[i * (NC * DC) + n * DC + d], s);
    float s2 = s * s;
#pragma unroll
    for (int off = 8; off >= 1; off >>= 1) s2 += __shfl_xor(s2, off, 16);
    float o = s / sqrtf(s2 + 1e-7f);
    if (FINAL) {
        out[b * (NC * DC) + n * DC + d] = o;
    } else {
        oS[n4][d] = o;
        __syncthreads();
        // wtil[b][n][i]: thread (n4, i4 = t&15) computes i = i4*4..i4*4+3
        int i4 = t & 15;
        float4 wv;
        float* wvp = (float*)&wv;
#pragma unroll
        for (int k = 0; k < 4; ++k) {
            int i = i4 * 4 + k;
            float acc = 0.f;
#pragma unroll
            for (int dd = 0; dd < 16; ++dd)
                acc = fmaf(W[i * (NC * DC) + n * DC + dd], oS[n4][dd], acc);
            wvp[k] = acc;
        }
        ((float4*)wtil)[(b * (NC * 64) + n * 64 + i4 * 4) >> 2] = wv;
    }
}

// ---------------------------------------------------------------------------
// k_route v6 (measured best, 99.6 us chain): grid 512 (b = bid>>4, ch =
// bid&15 -> 128 l's), 256 threads = 4 waves (2/SIMD at 2 blocks/CU);
// wave w owns l-rows [w*32, w*32+32).
// Phase A: per-lane 4l x 4n logits, n = lc + 8*jj (bank-conflict-free wf),
//          in-register softmax over n (shfl_xor over lc bits), c -> cS.
// Phase B: per-lane 4n x 8d V-tile over the wave's 32 l's.
// Fold: waves {1,3} write, {0,2} add (red overlays uS), halves fold + store
// block partial V[32][64] -> vpart[bid][2048]. No atomics, no fences.
// Nulls measured: 8-wave version (r7), f16+fdot2 version (r9) — do not redo.
// ---------------------------------------------------------------------------
__global__ __launch_bounds__(256) void k_route(const float* __restrict__ u,
                                               const float* __restrict__ wtil,
                                               float* __restrict__ vpart) {
    int b    = blockIdx.x >> 4;
    int ch   = blockIdx.x & 15;
    int l0   = ch * 128;
    int t    = threadIdx.x;
    int w    = t >> 6;
    int lane = t & 63;
    int lr   = lane & 7;   // l = w*32 + lr + 8*i
    int lc   = lane >> 3;  // n = lc + 8*jj
    int dr   = lane & 7;   // phase B: d = dr*8 .. dr*8+7
    int ng   = lane >> 3;  // phase B: n = ng + 8*jj

    __shared__ float uS[128 * 68];        // 34816 B; red[2][2048] overlay later
    __shared__ float wS[32 * 68];         //  8704 B
    __shared__ float cS[128 * 36];        // 18432 B: c rows, stride 9 float4
    float4* uS4 = (float4*)uS;
    float4* wS4 = (float4*)wS;
    float4* c4  = (float4*)cS;

    // ---- stage u-tile [128][64] and w-tile [32][64] (coalesced) ----
    const float4* ug = (const float4*)(u + (b * LSEQ + l0) * 64);
#pragma unroll
    for (int r = 0; r < 8; ++r) {
        int idx = t + 256 * r;                 // 0..2047 = row*16 + col4
        uS4[(idx >> 4) * 17 + (idx & 15)] = ug[idx];
    }
    const float4* wg = (const float4*)(wtil + b * (NC * 64));
#pragma unroll
    for (int r = 0; r < 2; ++r) {
        int idx = t + 256 * r;                 // 0..511
        wS4[(idx >> 4) * 17 + (idx & 15)] = wg[idx];
    }
    __syncthreads();

    // ---- phase A: logits (per-lane 4l x 4n register tile) ----
    float acc[4][4];
#pragma unroll
    for (int i = 0; i < 4; ++i)
#pragma unroll
        for (int jj = 0; jj < 4; ++jj) acc[i][jj] = 0.f;
    int arow = w * 32 + lr;
#pragma unroll 4
    for (int k4 = 0; k4 < 16; ++k4) {
        float4 wf[4];
#pragma unroll
        for (int jj = 0; jj < 4; ++jj) wf[jj] = wS4[(lc + 8 * jj) * 17 + k4];
#pragma unroll
        for (int i = 0; i < 4; ++i) {
            float4 a = uS4[(arow + 8 * i) * 17 + k4];
#pragma unroll
            for (int jj = 0; jj < 4; ++jj) {
                acc[i][jj] = fmaf(a.x, wf[jj].x, acc[i][jj]);
                acc[i][jj] = fmaf(a.y, wf[jj].y, acc[i][jj]);
                acc[i][jj] = fmaf(a.z, wf[jj].z, acc[i][jj]);
                acc[i][jj] = fmaf(a.w, wf[jj].w, acc[i][jj]);
            }
        }
    }

    // ---- softmax over n (4 regs x 8 lc-groups) per l-row i ----
#pragma unroll
    for (int i = 0; i < 4; ++i) {
        float m = fmaxf(fmaxf(acc[i][0], acc[i][1]), fmaxf(acc[i][2], acc[i][3]));
        m = fmaxf(m, __shfl_xor(m, 8));
        m = fmaxf(m, __shfl_xor(m, 16));
        m = fmaxf(m, __shfl_xor(m, 32));
        float e0 = __expf(acc[i][0] - m), e1 = __expf(acc[i][1] - m);
        float e2 = __expf(acc[i][2] - m), e3 = __expf(acc[i][3] - m);
        float ss = e0 + e1 + e2 + e3;
        ss += __shfl_xor(ss, 8);
        ss += __shfl_xor(ss, 16);
        ss += __shfl_xor(ss, 32);
        float inv = 1.f / ss;
        float4 cvv = {e0 * inv, e1 * inv, e2 * inv, e3 * inv};
        c4[(arow + 8 * i) * 9 + lc] = cvv;     // xyzw = n = lc, lc+8, lc+16, lc+24
    }
    __syncthreads();

    // ---- phase B: V[n = ng+8jj][d = dr*8..+7] += sum_l c[l][n]*u[l][d] ----
    float vacc[4][8];
#pragma unroll
    for (int jj = 0; jj < 4; ++jj)
#pragma unroll
        for (int k = 0; k < 8; ++k) vacc[jj][k] = 0.f;
#pragma unroll 8
    for (int lrel = 0; lrel < 32; ++lrel) {
        int row = w * 32 + lrel;
        float4 cv = c4[row * 9 + ng];
        const float4* ur = uS4 + row * 17 + dr * 2;
        float4 u0 = ur[0], u1 = ur[1];
        float* cp = (float*)&cv;
#pragma unroll
        for (int jj = 0; jj < 4; ++jj) {
            float c = cp[jj];
            vacc[jj][0] = fmaf(c, u0.x, vacc[jj][0]);
            vacc[jj][1] = fmaf(c, u0.y, vacc[jj][1]);
            vacc[jj][2] = fmaf(c, u0.z, vacc[jj][2]);
            vacc[jj][3] = fmaf(c, u0.w, vacc[jj][3]);
            vacc[jj][4] = fmaf(c, u1.x, vacc[jj][4]);
            vacc[jj][5] = fmaf(c, u1.y, vacc[jj][5]);
            vacc[jj][6] = fmaf(c, u1.z, vacc[jj][6]);
            vacc[jj][7] = fmaf(c, u1.w, vacc[jj][7]);
        }
    }
    __syncthreads();                   // all uS reads done -> overlay red on uS

    // ---- cross-wave fold: waves 1,3 write; 0,2 add; halves fold + store ----
    float* red   = uS;                 // [2][32][64] floats (16 KB)
    float* rbase = red + (w >> 1) * 2048;
    if (w & 1) {
#pragma unroll
        for (int jj = 0; jj < 4; ++jj) {
            float4* rp = (float4*)(rbase + (ng + 8 * jj) * 64 + dr * 8);
            float4 r0 = {vacc[jj][0], vacc[jj][1], vacc[jj][2], vacc[jj][3]};
            float4 r1 = {vacc[jj][4], vacc[jj][5], vacc[jj][6], vacc[jj][7]};
            rp[0] = r0;
            rp[1] = r1;
        }
    }
    __syncthreads();
    if (!(w & 1)) {
#pragma unroll
        for (int jj = 0; jj < 4; ++jj) {
            float4* rp = (float4*)(rbase + (ng + 8 * jj) * 64 + dr * 8);
            float4 r0 = rp[0], r1 = rp[1];
            r0.x += vacc[jj][0]; r0.y += vacc[jj][1];
            r0.z += vacc[jj][2]; r0.w += vacc[jj][3];
            r1.x += vacc[jj][4]; r1.y += vacc[jj][5];
            r1.z += vacc[jj][6]; r1.w += vacc[jj][7];
            rp[0] = r0;
            rp[1] = r1;
        }
    }
    __syncthreads();
    // fold the 2 halves and store the block partial (coalesced)
    float4* red4 = (float4*)red;
    float4* vp4  = (float4*)(vpart + blockIdx.x * 2048);
#pragma unroll
    for (int s = 0; s < 2; ++s) {
        int idx4 = t + 256 * s;               // 0..511
        float4 a  = red4[idx4];
        float4 c2 = red4[512 + idx4];
        float4 o  = {a.x + c2.x, a.y + c2.y, a.z + c2.z, a.w + c2.w};
        vp4[idx4] = o;
    }
}

extern "C" void kernel_launch(void* const* d_in, const int* in_sizes, int n_in,
                              void* d_out, int out_size, void* d_ws, size_t ws_size,
                              hipStream_t stream) {
    const float* u = (const float*)d_in[0];  // [32, 2048, 64] f32
    const float* W = (const float*)d_in[1];  // [1, 64, 512]  f32
    float* out = (float*)d_out;              // [32, 32, 16]  f32
    float* ws  = (float*)d_ws;
    float* v0p   = ws;                 // 256*64      = 16384 floats
    float* wt    = ws + 16384;         // 32*32*64    = 65536 floats
    float* vpart = ws + 16384 + 65536; // 512*2048    = 1048576 floats (~4 MB)

    // iter 0: uniform c = 1/32 -> column sum
    k_sum_u<<<256, 256, 0, stream>>>(u, v0p);
    k_caps<true, false><<<256, 64, 0, stream>>>(v0p, W, wt, nullptr, 1.0f / 32.0f);
    // iter 1
    k_route<<<512, 256, 0, stream>>>(u, wt, vpart);
    k_caps<false, false><<<256, 64, 0, stream>>>(vpart, W, wt, nullptr, 1.0f);
    // iter 2
    k_route<<<512, 256, 0, stream>>>(u, wt, vpart);
    k_caps<false, true><<<256, 64, 0, stream>>>(vpart, W, nullptr, out, 1.0f);
}